// Round 4
// baseline (1316.781 us; speedup 1.0000x reference)
//
#include <hip/hip_runtime.h>

#define N_TOT 32186
#define NV    28504
#define NS    3682
#define DIM   512
#define HEADS 8
#define DH    64
#define FL    500
#define NQ1   4182   /* FL + NS */
#define NQP   4224   /* NQ1 padded to multiple of 64 */
#define KSPL  2112   /* split-K boundary for attn1 (33 chunks of 64) */
#define SK    3586
#define NTOK  64
#define ONION 15
#define SC    4
#define SCALE 0.125f
#define EPS   1e-5f

typedef unsigned short u16;
typedef __bf16 bf16x8 __attribute__((ext_vector_type(8)));
typedef float  f32x4  __attribute__((ext_vector_type(4)));

static __device__ inline void bsplit(float f, u16& hi, u16& lo) {
    __bf16 h = (__bf16)f;
    __bf16 l = (__bf16)(f - (float)h);
    hi = __builtin_bit_cast(u16, h);
    lo = __builtin_bit_cast(u16, l);
}
static __device__ inline uint2 pk2(const u16* s) {
    uint2 w;
    w.x = (unsigned)s[0] | ((unsigned)s[1] << 16);
    w.y = (unsigned)s[2] | ((unsigned)s[3] << 16);
    return w;
}

// ---------------------------------------------------------------------------
// K0: split 3 weight matrices (512x512) into transposed bf16 hi/lo
// ---------------------------------------------------------------------------
__global__ __launch_bounds__(256) void k_split_wT(
    const float* __restrict__ W0, const float* __restrict__ W1, const float* __restrict__ W2,
    u16* __restrict__ h0, u16* __restrict__ l0,
    u16* __restrict__ h1, u16* __restrict__ l1,
    u16* __restrict__ h2, u16* __restrict__ l2)
{
    const float* W = (blockIdx.z == 0) ? W0 : (blockIdx.z == 1) ? W1 : W2;
    u16* th = (blockIdx.z == 0) ? h0 : (blockIdx.z == 1) ? h1 : h2;
    u16* tl = (blockIdx.z == 0) ? l0 : (blockIdx.z == 1) ? l1 : l2;
    __shared__ float T[32][33];
    const int tid = threadIdx.x;
    const int k0 = blockIdx.x*32, n0 = blockIdx.y*32;
    {
        int r = tid >> 3, c = (tid & 7) << 2;
        *(float4*)&T[r][c] = *(const float4*)(W + (size_t)(k0+r)*512 + n0 + c);
    }
    __syncthreads();
    int n = tid >> 3, kk = (tid & 7) << 2;
    u16 hh[4], ll[4];
    #pragma unroll
    for (int j = 0; j < 4; ++j) bsplit(T[kk+j][n], hh[j], ll[j]);
    *(uint2*)(th + (size_t)(n0+n)*512 + k0 + kk) = pk2(hh);
    *(uint2*)(tl + (size_t)(n0+n)*512 + k0 + kk) = pk2(ll);
}

// ---------------------------------------------------------------------------
// K1: C = A @ B + bias via split-bf16 MFMA (hh + hl + lh).
// ---------------------------------------------------------------------------
__global__ __launch_bounds__(256) void k_mm_bf16s(const float* __restrict__ A,
    const u16* __restrict__ Bth, const u16* __restrict__ Btl,
    const float* __restrict__ bias, float* __restrict__ C, int M)
{
    __shared__ __align__(16) u16 Ash[128][72], Asl[128][72];
    __shared__ __align__(16) u16 Bsh[64][72],  Bsl[64][72];
    const int tid = threadIdx.x;
    const int wave = tid >> 6, lane = tid & 63;
    const int m = lane & 15, quad = lane >> 4;
    const int bn = blockIdx.x * 64;
    const int bm = blockIdx.y * 128;
    const int wm = wave * 32;

    const int ar = tid >> 1;
    const int ac = (tid & 1) << 5;
    const int br = tid >> 2;
    const int bc = (tid & 3) << 4;

    f32x4 acc[2][4];
    #pragma unroll
    for (int mt = 0; mt < 2; ++mt)
        #pragma unroll
        for (int nt = 0; nt < 4; ++nt)
            #pragma unroll
            for (int r = 0; r < 4; ++r) acc[mt][nt][r] = 0.f;

    float4 pa[8];
    uint4 pbh[2], pbl[2];
    {
        bool va = (bm + ar) < M;
        const float* ap = A + (size_t)(bm+ar)*512 + ac;
        #pragma unroll
        for (int u = 0; u < 8; ++u)
            pa[u] = va ? *(const float4*)(ap + u*4) : float4{0,0,0,0};
        size_t bb = (size_t)(bn+br)*512 + bc;
        pbh[0] = *(const uint4*)(Bth + bb); pbh[1] = *(const uint4*)(Bth + bb + 8);
        pbl[0] = *(const uint4*)(Btl + bb); pbl[1] = *(const uint4*)(Btl + bb + 8);
    }

    for (int k0 = 0; k0 < 512; k0 += 64) {
        __syncthreads();
        #pragma unroll
        for (int u = 0; u < 8; ++u) {
            u16 hh[4], ll[4];
            bsplit(pa[u].x, hh[0], ll[0]);
            bsplit(pa[u].y, hh[1], ll[1]);
            bsplit(pa[u].z, hh[2], ll[2]);
            bsplit(pa[u].w, hh[3], ll[3]);
            *(uint2*)&Ash[ar][ac + u*4] = pk2(hh);
            *(uint2*)&Asl[ar][ac + u*4] = pk2(ll);
        }
        *(uint4*)&Bsh[br][bc]   = pbh[0];  *(uint4*)&Bsh[br][bc+8] = pbh[1];
        *(uint4*)&Bsl[br][bc]   = pbl[0];  *(uint4*)&Bsl[br][bc+8] = pbl[1];
        __syncthreads();
        const int kn = k0 + 64;
        if (kn < 512) {
            bool va = (bm + ar) < M;
            const float* ap = A + (size_t)(bm+ar)*512 + kn + ac;
            #pragma unroll
            for (int u = 0; u < 8; ++u)
                pa[u] = va ? *(const float4*)(ap + u*4) : float4{0,0,0,0};
            size_t bb = (size_t)(bn+br)*512 + kn + bc;
            pbh[0] = *(const uint4*)(Bth + bb); pbh[1] = *(const uint4*)(Bth + bb + 8);
            pbl[0] = *(const uint4*)(Btl + bb); pbl[1] = *(const uint4*)(Btl + bb + 8);
        }
        #pragma unroll
        for (int ks = 0; ks < 2; ++ks) {
            bf16x8 ah[2], al[2];
            #pragma unroll
            for (int mt = 0; mt < 2; ++mt) {
                ah[mt] = *(const bf16x8*)&Ash[wm + mt*16 + m][ks*32 + quad*8];
                al[mt] = *(const bf16x8*)&Asl[wm + mt*16 + m][ks*32 + quad*8];
            }
            bf16x8 bh[4], bl[4];
            #pragma unroll
            for (int nt = 0; nt < 4; ++nt) {
                bh[nt] = *(const bf16x8*)&Bsh[nt*16 + m][ks*32 + quad*8];
                bl[nt] = *(const bf16x8*)&Bsl[nt*16 + m][ks*32 + quad*8];
            }
            #pragma unroll
            for (int mt = 0; mt < 2; ++mt)
                #pragma unroll
                for (int nt = 0; nt < 4; ++nt)
                    acc[mt][nt] = __builtin_amdgcn_mfma_f32_16x16x32_bf16(ah[mt], bh[nt], acc[mt][nt], 0,0,0);
            #pragma unroll
            for (int mt = 0; mt < 2; ++mt)
                #pragma unroll
                for (int nt = 0; nt < 4; ++nt)
                    acc[mt][nt] = __builtin_amdgcn_mfma_f32_16x16x32_bf16(ah[mt], bl[nt], acc[mt][nt], 0,0,0);
            #pragma unroll
            for (int mt = 0; mt < 2; ++mt)
                #pragma unroll
                for (int nt = 0; nt < 4; ++nt)
                    acc[mt][nt] = __builtin_amdgcn_mfma_f32_16x16x32_bf16(al[mt], bh[nt], acc[mt][nt], 0,0,0);
        }
    }

    #pragma unroll
    for (int mt = 0; mt < 2; ++mt)
        #pragma unroll
        for (int nt = 0; nt < 4; ++nt) {
            float bsv = bias[bn + nt*16 + m];
            #pragma unroll
            for (int r = 0; r < 4; ++r) {
                int row = bm + wm + mt*16 + quad*4 + r;
                if (row < M)
                    C[(size_t)row*512 + bn + nt*16 + m] = acc[mt][nt][r] + bsv;
            }
        }
}

// ---------------------------------------------------------------------------
// K2: qkv for attention-1 (split-bf16 outputs, V transposed, NQP padded)
// ---------------------------------------------------------------------------
__global__ __launch_bounds__(256) void k_qkv1(const float* __restrict__ fx,
    const int* __restrict__ surf_idx, const int* __restrict__ velo_idx,
    const int* __restrict__ first_lap,
    const float* __restrict__ Wq, const float* __restrict__ Wk, const float* __restrict__ Wv,
    u16* __restrict__ Qhi, u16* __restrict__ Qlo,
    u16* __restrict__ Khi, u16* __restrict__ Klo,
    u16* __restrict__ Vthi, u16* __restrict__ Vtlo)
{
    __shared__ __align__(16) float As[16][64];
    __shared__ __align__(16) float Bs[3][16][64];
    const int tid = threadIdx.x;
    const int h = blockIdx.y;
    const int r0 = blockIdx.x * 64;
    const int tx = tid & 15, ty = tid >> 4;
    const int lr = tid >> 2, lc = (tid & 3) << 2;
    const int rr = r0 + lr;
    long src = -1;
    if (rr < NQ1) src = (rr < FL) ? velo_idx[first_lap[rr]] : surf_idx[rr - FL];
    float acc[3][4][4] = {};
    for (int k0 = 0; k0 < 64; k0 += 16) {
        float4 av = {0,0,0,0};
        if (src >= 0) av = *(const float4*)(fx + (size_t)src*512 + h*64 + k0 + lc);
        As[lc+0][lr]=av.x; As[lc+1][lr]=av.y; As[lc+2][lr]=av.z; As[lc+3][lr]=av.w;
        const int wr = tid >> 4, wc = (tid & 15) << 2;
        *(float4*)&Bs[0][wr][wc] = *(const float4*)(Wq + (k0+wr)*64 + wc);
        *(float4*)&Bs[1][wr][wc] = *(const float4*)(Wk + (k0+wr)*64 + wc);
        *(float4*)&Bs[2][wr][wc] = *(const float4*)(Wv + (k0+wr)*64 + wc);
        __syncthreads();
        #pragma unroll
        for (int kk = 0; kk < 16; ++kk) {
            float4 a = *(const float4*)&As[kk][ty<<2];
            const float aa[4] = {a.x,a.y,a.z,a.w};
            #pragma unroll
            for (int mm = 0; mm < 3; ++mm) {
                float4 bv = *(const float4*)&Bs[mm][kk][tx<<2];
                const float bb[4] = {bv.x,bv.y,bv.z,bv.w};
                #pragma unroll
                for (int i = 0; i < 4; ++i)
                    #pragma unroll
                    for (int j = 0; j < 4; ++j)
                        acc[mm][i][j] = fmaf(aa[i], bb[j], acc[mm][i][j]);
            }
        }
        __syncthreads();
    }
    #pragma unroll
    for (int i = 0; i < 4; ++i) {
        int r = r0 + (ty<<2) + i;
        size_t qb = ((size_t)h*NQP + r)*64 + (tx<<2);
        u16 qh_[4], ql_[4], kh_[4], kl_[4];
        #pragma unroll
        for (int j = 0; j < 4; ++j) {
            bsplit(acc[0][i][j]*SCALE, qh_[j], ql_[j]);
            bsplit(acc[1][i][j],       kh_[j], kl_[j]);
        }
        *(uint2*)(Qhi + qb) = pk2(qh_);
        *(uint2*)(Qlo + qb) = pk2(ql_);
        *(uint2*)(Khi + qb) = pk2(kh_);
        *(uint2*)(Klo + qb) = pk2(kl_);
        #pragma unroll
        for (int j = 0; j < 4; ++j) {
            u16 vh_, vl_;
            bsplit(acc[2][i][j], vh_, vl_);
            size_t vb = ((size_t)h*64 + (tx<<2) + j)*NQP + r;
            Vthi[vb] = vh_;
            Vtlo[vb] = vl_;
        }
    }
}

// ---------------------------------------------------------------------------
// K3: split-bf16 MFMA flash attention, split-K x2 (flash-decoding style).
// grid (33, 8, 2), block 256 (4 waves). Each wave: 32 q-rows.
// z selects key segment [0,KSPL) or [KSPL,NQ1). Emits unnormalized O-partial
// and per-row (m,l); k_attn_merge combines the two segments.
// ---------------------------------------------------------------------------
__global__ __launch_bounds__(256) void k_attn1(
    const u16* __restrict__ Qhi, const u16* __restrict__ Qlo,
    const u16* __restrict__ Khi, const u16* __restrict__ Klo,
    const u16* __restrict__ Vthi, const u16* __restrict__ Vtlo,
    float* __restrict__ Op0, float* __restrict__ Op1,
    float2* __restrict__ Ml0, float2* __restrict__ Ml1)
{
    __shared__ __align__(16) u16 Ksh[64][72];
    __shared__ __align__(16) u16 Ksl[64][72];
    __shared__ __align__(16) u16 Vsh[64][72];
    __shared__ __align__(16) u16 Vsl[64][72];
    __shared__ __align__(16) float Ps[4][32*68];

    const int tid = threadIdx.x;
    const int wave = tid >> 6;
    const int lane = tid & 63;
    const int m = lane & 15, quad = lane >> 4;
    const int h = blockIdx.y;
    const int q0 = blockIdx.x*128 + wave*32;
    const int zz = blockIdx.z;
    const int kbeg = zz ? KSPL : 0;
    const int kend = zz ? NQ1 : KSPL;
    float*  Op = zz ? Op1 : Op0;
    float2* Ml = zz ? Ml1 : Ml0;

    const u16* Kgh = Khi + (size_t)h*NQP*64;
    const u16* Kgl = Klo + (size_t)h*NQP*64;
    const u16* Vgh = Vthi + (size_t)h*64*NQP;
    const u16* Vgl = Vtlo + (size_t)h*64*NQP;

    bf16x8 qh[2][2], ql[2][2];
    #pragma unroll
    for (int t = 0; t < 2; ++t)
        #pragma unroll
        for (int ks = 0; ks < 2; ++ks) {
            int q = q0 + t*16 + m;
            size_t off = ((size_t)h*NQP + q)*64 + ks*32 + quad*8;
            qh[t][ks] = *(const bf16x8*)(Qhi + off);
            ql[t][ks] = *(const bf16x8*)(Qlo + off);
        }

    const int sr = tid >> 2;
    const int sc = (tid & 3) << 4;
    uint4 pre[8];
    {
        size_t kb = ((size_t)kbeg + sr)*64 + sc;
        pre[0] = *(const uint4*)(Kgh + kb);     pre[1] = *(const uint4*)(Kgh + kb + 8);
        pre[2] = *(const uint4*)(Kgl + kb);     pre[3] = *(const uint4*)(Kgl + kb + 8);
        size_t vb = (size_t)sr*NQP + kbeg + sc;
        pre[4] = *(const uint4*)(Vgh + vb);     pre[5] = *(const uint4*)(Vgh + vb + 8);
        pre[6] = *(const uint4*)(Vgl + vb);     pre[7] = *(const uint4*)(Vgl + vb + 8);
    }

    f32x4 Oc[2][4];
    float mrun[2][4], lrun[2][4];
    #pragma unroll
    for (int t = 0; t < 2; ++t)
        #pragma unroll
        for (int r = 0; r < 4; ++r) {
            mrun[t][r] = -1e30f; lrun[t][r] = 0.f;
            #pragma unroll
            for (int dt = 0; dt < 4; ++dt) Oc[t][dt][r] = 0.f;
        }
    float* Pw = &Ps[wave][0];

    for (int k0 = kbeg; k0 < kend; k0 += 64) {
        __syncthreads();
        *(uint4*)&Ksh[sr][sc] = pre[0];  *(uint4*)&Ksh[sr][sc+8] = pre[1];
        *(uint4*)&Ksl[sr][sc] = pre[2];  *(uint4*)&Ksl[sr][sc+8] = pre[3];
        *(uint4*)&Vsh[sr][sc] = pre[4];  *(uint4*)&Vsh[sr][sc+8] = pre[5];
        *(uint4*)&Vsl[sr][sc] = pre[6];  *(uint4*)&Vsl[sr][sc+8] = pre[7];
        __syncthreads();
        const int kn = k0 + 64;
        if (kn < kend) {
            size_t kb = ((size_t)kn + sr)*64 + sc;
            pre[0] = *(const uint4*)(Kgh + kb);     pre[1] = *(const uint4*)(Kgh + kb + 8);
            pre[2] = *(const uint4*)(Kgl + kb);     pre[3] = *(const uint4*)(Kgl + kb + 8);
            size_t vb = (size_t)sr*NQP + kn + sc;
            pre[4] = *(const uint4*)(Vgh + vb);     pre[5] = *(const uint4*)(Vgh + vb + 8);
            pre[6] = *(const uint4*)(Vgl + vb);     pre[7] = *(const uint4*)(Vgl + vb + 8);
        }

        f32x4 S[2][4];
        #pragma unroll
        for (int t = 0; t < 2; ++t)
            #pragma unroll
            for (int n = 0; n < 4; ++n)
                #pragma unroll
                for (int r = 0; r < 4; ++r) S[t][n][r] = 0.f;
        #pragma unroll
        for (int ks = 0; ks < 2; ++ks) {
            bf16x8 kh[4], kl[4];
            #pragma unroll
            for (int n = 0; n < 4; ++n) {
                kh[n] = *(const bf16x8*)&Ksh[n*16 + m][ks*32 + quad*8];
                kl[n] = *(const bf16x8*)&Ksl[n*16 + m][ks*32 + quad*8];
            }
            #pragma unroll
            for (int t = 0; t < 2; ++t)
                #pragma unroll
                for (int n = 0; n < 4; ++n)
                    S[t][n] = __builtin_amdgcn_mfma_f32_16x16x32_bf16(qh[t][ks], kh[n], S[t][n], 0,0,0);
            #pragma unroll
            for (int t = 0; t < 2; ++t)
                #pragma unroll
                for (int n = 0; n < 4; ++n)
                    S[t][n] = __builtin_amdgcn_mfma_f32_16x16x32_bf16(qh[t][ks], kl[n], S[t][n], 0,0,0);
            #pragma unroll
            for (int t = 0; t < 2; ++t)
                #pragma unroll
                for (int n = 0; n < 4; ++n)
                    S[t][n] = __builtin_amdgcn_mfma_f32_16x16x32_bf16(ql[t][ks], kh[n], S[t][n], 0,0,0);
        }
        if (kn > NQ1) {   // mask padded keys (last chunk of segment 1)
            #pragma unroll
            for (int n = 0; n < 4; ++n)
                if (k0 + n*16 + m >= NQ1) {
                    #pragma unroll
                    for (int t = 0; t < 2; ++t)
                        #pragma unroll
                        for (int r = 0; r < 4; ++r) S[t][n][r] = -1e30f;
                }
        }

        float alpha[2][4];
        #pragma unroll
        for (int t = 0; t < 2; ++t) {
            float sm[4];
            #pragma unroll
            for (int r = 0; r < 4; ++r) {
                float v = fmaxf(fmaxf(S[t][0][r], S[t][1][r]), fmaxf(S[t][2][r], S[t][3][r]));
                v = fmaxf(v, __shfl_xor(v, 1));
                v = fmaxf(v, __shfl_xor(v, 2));
                v = fmaxf(v, __shfl_xor(v, 4));
                v = fmaxf(v, __shfl_xor(v, 8));
                float mn = fmaxf(mrun[t][r], v);
                alpha[t][r] = __expf(mrun[t][r] - mn);
                mrun[t][r] = mn;
                sm[r] = 0.f;
            }
            #pragma unroll
            for (int n = 0; n < 4; ++n)
                #pragma unroll
                for (int r = 0; r < 4; ++r) {
                    float p = __expf(S[t][n][r] - mrun[t][r]);
                    S[t][n][r] = p;
                    sm[r] += p;
                }
            #pragma unroll
            for (int r = 0; r < 4; ++r) {
                float v = sm[r];
                v += __shfl_xor(v, 1);
                v += __shfl_xor(v, 2);
                v += __shfl_xor(v, 4);
                v += __shfl_xor(v, 8);
                lrun[t][r] = lrun[t][r]*alpha[t][r] + v;
            }
        }
        #pragma unroll
        for (int t = 0; t < 2; ++t)
            #pragma unroll
            for (int dt = 0; dt < 4; ++dt)
                #pragma unroll
                for (int r = 0; r < 4; ++r) Oc[t][dt][r] *= alpha[t][r];

        #pragma unroll
        for (int t = 0; t < 2; ++t)
            #pragma unroll
            for (int n = 0; n < 4; ++n)
                #pragma unroll
                for (int r = 0; r < 4; ++r)
                    Pw[(t*16 + quad*4 + r)*68 + n*16 + m] = S[t][n][r];

        #pragma unroll
        for (int ks = 0; ks < 2; ++ks) {
            bf16x8 ah[2], al[2];
            #pragma unroll
            for (int t = 0; t < 2; ++t) {
                const float* pp = Pw + (t*16 + m)*68 + ks*32 + quad*8;
                float4 xa = *(const float4*)pp;
                float4 xb = *(const float4*)(pp + 4);
                float e0[8] = {xa.x, xa.y, xa.z, xa.w, xb.x, xb.y, xb.z, xb.w};
                #pragma unroll
                for (int j = 0; j < 8; ++j) {
                    __bf16 hb = (__bf16)e0[j];
                    ah[t][j] = hb;
                    al[t][j] = (__bf16)(e0[j] - (float)hb);
                }
            }
            bf16x8 vh[4], vl[4];
            #pragma unroll
            for (int dt = 0; dt < 4; ++dt) {
                vh[dt] = *(const bf16x8*)&Vsh[dt*16 + m][ks*32 + quad*8];
                vl[dt] = *(const bf16x8*)&Vsl[dt*16 + m][ks*32 + quad*8];
            }
            #pragma unroll
            for (int t = 0; t < 2; ++t)
                #pragma unroll
                for (int dt = 0; dt < 4; ++dt)
                    Oc[t][dt] = __builtin_amdgcn_mfma_f32_16x16x32_bf16(ah[t], vh[dt], Oc[t][dt], 0,0,0);
            #pragma unroll
            for (int t = 0; t < 2; ++t)
                #pragma unroll
                for (int dt = 0; dt < 4; ++dt)
                    Oc[t][dt] = __builtin_amdgcn_mfma_f32_16x16x32_bf16(ah[t], vl[dt], Oc[t][dt], 0,0,0);
            #pragma unroll
            for (int t = 0; t < 2; ++t)
                #pragma unroll
                for (int dt = 0; dt < 4; ++dt)
                    Oc[t][dt] = __builtin_amdgcn_mfma_f32_16x16x32_bf16(al[t], vh[dt], Oc[t][dt], 0,0,0);
        }
    }

    // epilogue: unnormalized partial + (m,l) per row
    #pragma unroll
    for (int t = 0; t < 2; ++t) {
        #pragma unroll
        for (int r = 0; r < 4; ++r) {
            int q = q0 + t*16 + quad*4 + r;
            if (q < NQ1 && m == 0)
                Ml[(size_t)h*NQ1 + q] = make_float2(mrun[t][r], lrun[t][r]);
        }
        #pragma unroll
        for (int dt = 0; dt < 4; ++dt)
            #pragma unroll
            for (int r = 0; r < 4; ++r) {
                int q = q0 + t*16 + quad*4 + r;
                if (q < NQ1)
                    Op[((size_t)h*NQ1 + q)*64 + dt*16 + m] = Oc[t][dt][r];
            }
    }
}

// ---------------------------------------------------------------------------
// K3b: merge the two K-segments (exact online-softmax combine), in place.
// ---------------------------------------------------------------------------
__global__ __launch_bounds__(256) void k_attn_merge(
    const float* __restrict__ Op0, const float* __restrict__ Op1,
    const float2* __restrict__ Ml0, const float2* __restrict__ Ml1,
    float* __restrict__ O)
{
    int idx = blockIdx.x*256 + threadIdx.x;
    if (idx >= HEADS*NQ1*16) return;
    int row = idx >> 4, d4 = (idx & 15) << 2;
    float2 a = Ml0[row], b = Ml1[row];
    float mx = fmaxf(a.x, b.x);
    float e0 = __expf(a.x - mx), e1 = __expf(b.x - mx);
    float inv = 1.f / (a.y*e0 + b.y*e1);
    float4 o0 = *(const float4*)(Op0 + (size_t)row*64 + d4);
    float4 o1 = *(const float4*)(Op1 + (size_t)row*64 + d4);
    float4 r;
    r.x = (o0.x*e0 + o1.x*e1)*inv;
    r.y = (o0.y*e0 + o1.y*e1)*inv;
    r.z = (o0.z*e0 + o1.z*e1)*inv;
    r.w = (o0.w*e0 + o1.w*e1)*inv;
    *(float4*)(O + (size_t)row*64 + d4) = r;
}

// ---------------------------------------------------------------------------
// K4a: per source row -> (token id, fx row)
// ---------------------------------------------------------------------------
__global__ void k_bucket_prep(const int* __restrict__ labels, const int* __restrict__ closest,
    const int* __restrict__ surf_idx, const int* __restrict__ velo_idx,
    const float* __restrict__ onion, int* __restrict__ tok_of, int* __restrict__ src_of)
{
    int r = blockIdx.x*256 + threadIdx.x;
    if (r < SK) {
        tok_of[r] = labels[r];
        int s = (r < 16) ? r : r + 96;
        src_of[r] = surf_idx[s];
    } else if (r < SK + NV) {
        int p = r - SK;
        int cl = labels[closest[p]];
        int l = 0;
        #pragma unroll
        for (int q = 1; q < ONION; ++q)
            if (onion[(size_t)q*NV + p] != 0.f) l = q;
        tok_of[r] = SC + l*SC + cl;
        src_of[r] = velo_idx[p];
    }
}

// ---------------------------------------------------------------------------
// K4b: token pooling partials
// ---------------------------------------------------------------------------
__global__ __launch_bounds__(256) void k_tokens_accum(const float* __restrict__ fx,
    const int* __restrict__ tok_of, const int* __restrict__ src_of, float* __restrict__ part)
{
    __shared__ float acc[64][256];
    const int tid = threadIdx.x;
    for (int i = tid; i < 64*256; i += 256) ((float*)acc)[i] = 0.f;
    __syncthreads();
    const int d0 = blockIdx.x << 8;
    const int R = SK + NV;
    const int per = (R + gridDim.y - 1) / gridDim.y;
    int rs = blockIdx.y * per;
    int re = rs + per; if (re > R) re = R;
    const float wS = 1.f / SK, wV = 1.f / NV;
    int r = rs;
    for (; r + 4 <= re; r += 4) {
        int t0 = tok_of[r], t1 = tok_of[r+1], t2 = tok_of[r+2], t3 = tok_of[r+3];
        int s0 = src_of[r], s1 = src_of[r+1], s2 = src_of[r+2], s3 = src_of[r+3];
        float v0 = fx[(size_t)s0*512 + d0 + tid] * ((r   < SK) ? wS : wV);
        float v1 = fx[(size_t)s1*512 + d0 + tid] * ((r+1 < SK) ? wS : wV);
        float v2 = fx[(size_t)s2*512 + d0 + tid] * ((r+2 < SK) ? wS : wV);
        float v3 = fx[(size_t)s3*512 + d0 + tid] * ((r+3 < SK) ? wS : wV);
        acc[t0][tid] += v0; acc[t1][tid] += v1; acc[t2][tid] += v2; acc[t3][tid] += v3;
    }
    for (; r < re; ++r) {
        float v = fx[(size_t)src_of[r]*512 + d0 + tid] * ((r < SK) ? wS : wV);
        acc[tok_of[r]][tid] += v;
    }
    __syncthreads();
    float* dst = part + ((size_t)blockIdx.x*gridDim.y + blockIdx.y)*64*256;
    for (int i = tid; i < 64*256; i += 256) dst[i] = acc[i >> 8][i & 255];
}

__global__ void k_tokens_reduce(const float* __restrict__ part, float* __restrict__ tokens)
{
    int idx = blockIdx.x*256 + threadIdx.x;   // < 64*512
    int t = idx >> 9;
    int dg = idx & 511;
    int cc = dg >> 8, d = dg & 255;
    float s = 0.f;
    for (int ch = 0; ch < 64; ++ch)
        s += part[(((size_t)cc*64 + ch)*64 + t)*256 + d];
    tokens[idx] = s;
}

// ---------------------------------------------------------------------------
// K5a: LayerNorm across the 64 tokens, per channel
// ---------------------------------------------------------------------------
__global__ void k_ln(const float* __restrict__ tokens, const float* __restrict__ gamma,
    const float* __restrict__ beta, float* __restrict__ tln)
{
    int ch = blockIdx.x*256 + threadIdx.x;
    if (ch >= 512) return;
    float vals[64];
    float mu = 0.f;
    #pragma unroll
    for (int t = 0; t < 64; ++t) { vals[t] = tokens[t*512 + ch]; mu += vals[t]; }
    mu *= (1.f/64.f);
    float var = 0.f;
    #pragma unroll
    for (int t = 0; t < 64; ++t) { float d = vals[t]-mu; var = fmaf(d, d, var); }
    var *= (1.f/64.f);
    float rstd = rsqrtf(var + EPS);
    #pragma unroll
    for (int t = 0; t < 64; ++t)
        tln[t*512 + ch] = (vals[t]-mu)*rstd*gamma[t] + beta[t];
}

// ---------------------------------------------------------------------------
// K5b: q2/k2/v2[h][t][e] for the 64-token attention
// ---------------------------------------------------------------------------
__global__ __launch_bounds__(256) void k_qkv2(const float* __restrict__ tln,
    const float* __restrict__ Wq, const float* __restrict__ Wk, const float* __restrict__ Wv,
    float* __restrict__ q2, float* __restrict__ k2, float* __restrict__ v2)
{
    __shared__ float Ts[64][64];
    __shared__ float Wt[3][64][65];
    const int h = blockIdx.x, tid = threadIdx.x;
    for (int i = tid; i < 4096; i += 256) {
        int t = i >> 6, d = i & 63;
        Ts[t][d] = tln[t*512 + h*64 + d];
    }
    for (int i = tid; i < 4096; i += 256) {
        int d = i >> 6, e = i & 63;
        Wt[0][e][d] = Wq[i]; Wt[1][e][d] = Wk[i]; Wt[2][e][d] = Wv[i];
    }
    __syncthreads();
    for (int o = tid; o < 4096; o += 256) {
        int t = o >> 6, e = o & 63;
        float s0 = 0.f, s1 = 0.f, s2 = 0.f;
        for (int d = 0; d < 64; ++d) {
            float xv = Ts[t][d];
            s0 = fmaf(xv, Wt[0][e][d], s0);
            s1 = fmaf(xv, Wt[1][e][d], s1);
            s2 = fmaf(xv, Wt[2][e][d], s2);
        }
        size_t idx = (size_t)h*4096 + o;
        q2[idx] = s0; k2[idx] = s1; v2[idx] = s2;
    }
}

// ---------------------------------------------------------------------------
// K5c: 64-token attention per head
// ---------------------------------------------------------------------------
__global__ __launch_bounds__(256) void k_attn2(const float* __restrict__ q2,
    const float* __restrict__ k2, const float* __restrict__ v2, float* __restrict__ ot)
{
    __shared__ float Qs[64][65], Ks[64][65], Vs[64][65], Ps2[64][65];
    const int h = blockIdx.x, tid = threadIdx.x;
    const float* qh = q2 + (size_t)h*4096;
    const float* kh = k2 + (size_t)h*4096;
    const float* vh = v2 + (size_t)h*4096;
    for (int i = tid; i < 4096; i += 256) {
        int t = i >> 6, e = i & 63;
        Qs[t][e] = qh[i]; Ks[t][e] = kh[i]; Vs[t][e] = vh[i];
    }
    __syncthreads();
    for (int o = tid; o < 4096; o += 256) {
        int t = o >> 6, j = o & 63;
        float s = 0.f;
        for (int e = 0; e < 64; ++e) s = fmaf(Qs[t][e], Ks[j][e], s);
        Ps2[t][j] = s * SCALE;
    }
    __syncthreads();
    if (tid < 64) {
        float mx = -1e30f;
        for (int j = 0; j < 64; ++j) mx = fmaxf(mx, Ps2[tid][j]);
        float sum = 0.f;
        for (int j = 0; j < 64; ++j) { float p = __expf(Ps2[tid][j]-mx); Ps2[tid][j] = p; sum += p; }
        float inv = 1.f / sum;
        for (int j = 0; j < 64; ++j) Ps2[tid][j] *= inv;
    }
    __syncthreads();
    for (int o = tid; o < 4096; o += 256) {
        int t = o >> 6, e = o & 63;
        float s = 0.f;
        for (int j = 0; j < 64; ++j) s = fmaf(Ps2[t][j], Vs[j][e], s);
        ot[(size_t)h*4096 + o] = s;
    }
}

// ---------------------------------------------------------------------------
// K5d: out_surf (flat reshape) and out_velo (head-concat) from out_tok
// ---------------------------------------------------------------------------
__global__ void k_build_ov(const float* __restrict__ ot, float* __restrict__ osurf,
    float* __restrict__ ovelo)
{
    int i = blockIdx.x*256 + threadIdx.x;
    if (i < 2048) {
        osurf[i] = ot[((i >> 8) << 12) + (i & 255)];
    }
    int g = i - 2048;
    if (g >= 0 && g < 60*512) {
        int j = g >> 9, cch = g & 511;
        int hh = cch >> 6, d = cch & 63;
        ovelo[g] = ot[(size_t)hh*4096 + (SC + j)*64 + d];
    }
}

// ---------------------------------------------------------------------------
// K6a: cs = surf_x@W_ws+b_ws  and  cc = surf_x@W_vc+b_vc (64-col concat)
// ---------------------------------------------------------------------------
__global__ __launch_bounds__(256) void k_coef_surf(const float* __restrict__ xm,
    const int* __restrict__ surf_idx,
    const float* __restrict__ W_ws, const float* __restrict__ b_ws,
    const float* __restrict__ W_vc, const float* __restrict__ b_vc,
    float* __restrict__ cs, float* __restrict__ cc)
{
    __shared__ __align__(16) float As[16][516];
    __shared__ float Ws[128][64];
    const int tid = threadIdx.x;
    const int s0 = blockIdx.x * 16;
    for (int i = tid; i < 16*128; i += 256) {
        int r = i >> 7, c4 = (i & 127) << 2;
        float4 a = {0,0,0,0};
        int s = s0 + r;
        if (s < NS) a = *(const float4*)(xm + (size_t)surf_idx[s]*512 + c4);
        *(float4*)&As[r][c4] = a;
    }
    const int c = tid & 63, rg = tid >> 6;
    float acc[4] = {0,0,0,0};
    for (int k0 = 0; k0 < 512; k0 += 128) {
        __syncthreads();
        for (int i = tid; i < 128*64; i += 256) {
            int kk = i >> 6, cw = i & 63;
            int k = k0 + kk;
            Ws[kk][cw] = (cw < 4) ? W_ws[k*4 + cw] : W_vc[k*60 + (cw-4)];
        }
        __syncthreads();
        #pragma unroll 8
        for (int kk = 0; kk < 128; kk += 4) {
            float w0 = Ws[kk][c], w1 = Ws[kk+1][c], w2 = Ws[kk+2][c], w3 = Ws[kk+3][c];
            #pragma unroll
            for (int u = 0; u < 4; ++u) {
                float4 a = *(const float4*)&As[rg + (u<<2)][k0 + kk];
                acc[u] = fmaf(a.x,w0, fmaf(a.y,w1, fmaf(a.z,w2, fmaf(a.w,w3, acc[u]))));
            }
        }
    }
    #pragma unroll
    for (int u = 0; u < 4; ++u) {
        int s = s0 + rg + (u<<2);
        if (s >= NS) continue;
        if (c < 4) cs[(size_t)s*4 + c] = acc[u] + b_ws[c];
        else cc[(size_t)s*60 + (c-4)] = acc[u] + b_vc[c-4];
    }
}

// ---------------------------------------------------------------------------
// K6b: cv = velo_x@W_vv+b_vv
// ---------------------------------------------------------------------------
__global__ __launch_bounds__(256) void k_coef_velo(const float* __restrict__ xm,
    const int* __restrict__ velo_idx, const float* __restrict__ W,
    const float* __restrict__ b, float* __restrict__ cv)
{
    __shared__ __align__(16) float As[16][516];
    __shared__ float Ws[128][64];
    const int tid = threadIdx.x;
    const int v0 = blockIdx.x * 16;
    for (int i = tid; i < 16*128; i += 256) {
        int r = i >> 7, c4 = (i & 127) << 2;
        float4 a = {0,0,0,0};
        int v = v0 + r;
        if (v < NV) a = *(const float4*)(xm + (size_t)velo_idx[v]*512 + c4);
        *(float4*)&As[r][c4] = a;
    }
    const int c = tid & 63, rg = tid >> 6;
    float acc[4] = {0,0,0,0};
    for (int k0 = 0; k0 < 512; k0 += 128) {
        __syncthreads();
        for (int i = tid; i < 128*64; i += 256) {
            int kk = i >> 6, cw = i & 63;
            Ws[kk][cw] = (cw < 60) ? W[(size_t)(k0+kk)*60 + cw] : 0.f;
        }
        __syncthreads();
        #pragma unroll 8
        for (int kk = 0; kk < 128; kk += 4) {
            float w0 = Ws[kk][c], w1 = Ws[kk+1][c], w2 = Ws[kk+2][c], w3 = Ws[kk+3][c];
            #pragma unroll
            for (int u = 0; u < 4; ++u) {
                float4 a = *(const float4*)&As[rg + (u<<2)][k0 + kk];
                acc[u] = fmaf(a.x,w0, fmaf(a.y,w1, fmaf(a.z,w2, fmaf(a.w,w3, acc[u]))));
            }
        }
    }
    if (c < 60) {
        float bb = b[c];
        #pragma unroll
        for (int u = 0; u < 4; ++u) {
            int v = v0 + rg + (u<<2);
            if (v < NV) cv[(size_t)v*60 + c] = acc[u] + bb;
        }
    }
}

// ---------------------------------------------------------------------------
// K7a: feat_velo = cv@out_velo (+ velo_first_lap rows<FL) -> nf scatter
// ---------------------------------------------------------------------------
__global__ __launch_bounds__(256) void k_feat_velo(const float* __restrict__ cv,
    const float* __restrict__ ovelo, const float* __restrict__ O1,
    const int* __restrict__ velo_idx, float* __restrict__ nf)
{
    __shared__ float Cs[16][64];
    const int tid = threadIdx.x;
    const int v0 = blockIdx.x * 16;
    for (int i = tid; i < 16*64; i += 256) {
        int r = i >> 6, j = i & 63;
        int v = v0 + r;
        Cs[r][j] = (j < 60 && v < NV) ? cv[(size_t)v*60 + j] : 0.f;
    }
    __syncthreads();
    const int c = tid, c2 = tid + 256;
    float a0[16], a1[16];
    #pragma unroll
    for (int r = 0; r < 16; ++r) { a0[r] = 0.f; a1[r] = 0.f; }
    #pragma unroll 4
    for (int j = 0; j < 60; ++j) {
        float e0 = ovelo[j*512 + c];
        float e1 = ovelo[j*512 + c2];
        #pragma unroll
        for (int r = 0; r < 16; ++r) {
            float cf = Cs[r][j];
            a0[r] = fmaf(cf, e0, a0[r]);
            a1[r] = fmaf(cf, e1, a1[r]);
        }
    }
    const int h0 = c >> 6, d0 = c & 63, h1 = c2 >> 6, d1 = c2 & 63;
    for (int r = 0; r < 16; ++r) {
        int v = v0 + r;
        if (v >= NV) break;
        float f0 = a0[r], f1 = a1[r];
        if (v < FL) {
            f0 += O1[((size_t)h0*NQ1 + v)*64 + d0];
            f1 += O1[((size_t)h1*NQ1 + v)*64 + d1];
        }
        size_t row = (size_t)velo_idx[v]*512;
        nf[row + c] = f0;
        nf[row + c2] = f1;
    }
}

// ---------------------------------------------------------------------------
// K7b: feat_surf = 0.5*(cs@out_surf + cc@out_velo) + surf_first_lap -> nf
// ---------------------------------------------------------------------------
__global__ __launch_bounds__(256) void k_feat_surf(const float* __restrict__ cs,
    const float* __restrict__ cc, const float* __restrict__ osurf,
    const float* __restrict__ ovelo, const float* __restrict__ O1,
    const int* __restrict__ surf_idx, float* __restrict__ nf)
{
    __shared__ float Cs[16][64];
    const int tid = threadIdx.x;
    const int s0 = blockIdx.x * 16;
    for (int i = tid; i < 16*64; i += 256) {
        int r = i >> 6, j = i & 63;
        int s = s0 + r;
        float v = 0.f;
        if (s < NS) v = (j < 4) ? cs[(size_t)s*4 + j] : cc[(size_t)s*60 + (j-4)];
        Cs[r][j] = v;
    }
    __syncthreads();
    const int c = tid, c2 = tid + 256;
    float a0[16], a1[16];
    #pragma unroll
    for (int r = 0; r < 16; ++r) { a0[r] = 0.f; a1[r] = 0.f; }
    #pragma unroll 4
    for (int j = 0; j < 64; ++j) {
        float e0 = (j < 4) ? osurf[j*512 + c]  : ovelo[(j-4)*512 + c];
        float e1 = (j < 4) ? osurf[j*512 + c2] : ovelo[(j-4)*512 + c2];
        #pragma unroll
        for (int r = 0; r < 16; ++r) {
            float cf = Cs[r][j];
            a0[r] = fmaf(cf, e0, a0[r]);
            a1[r] = fmaf(cf, e1, a1[r]);
        }
    }
    const int h0 = c >> 6, d0 = c & 63, h1 = c2 >> 6, d1 = c2 & 63;
    for (int r = 0; r < 16; ++r) {
        int s = s0 + r;
        if (s >= NS) break;
        float f0 = 0.5f*a0[r] + O1[((size_t)h0*NQ1 + FL + s)*64 + d0];
        float f1 = 0.5f*a1[r] + O1[((size_t)h1*NQ1 + FL + s)*64 + d1];
        size_t row = (size_t)surf_idx[s]*512;
        nf[row + c] = f0;
        nf[row + c2] = f1;
    }
}

// ---------------------------------------------------------------------------
extern "C" void kernel_launch(void* const* d_in, const int* in_sizes, int n_in,
                              void* d_out, int out_size, void* d_ws, size_t ws_size,
                              hipStream_t stream)
{
    const float* x       = (const float*)d_in[0];
    const float* onion   = (const float*)d_in[1];
    const float* W_fx    = (const float*)d_in[2];
    const float* b_fx    = (const float*)d_in[3];
    const float* W_x     = (const float*)d_in[4];
    const float* b_x     = (const float*)d_in[5];
    const float* Wq1     = (const float*)d_in[6];
    const float* Wk1     = (const float*)d_in[7];
    const float* Wv1     = (const float*)d_in[8];
    const float* Wq      = (const float*)d_in[9];
    const float* Wk      = (const float*)d_in[10];
    const float* Wv      = (const float*)d_in[11];
    const float* gamma   = (const float*)d_in[12];
    const float* beta    = (const float*)d_in[13];
    const float* W_ws    = (const float*)d_in[14];
    const float* b_ws    = (const float*)d_in[15];
    const float* W_vv    = (const float*)d_in[16];
    const float* b_vv    = (const float*)d_in[17];
    const float* W_vc    = (const float*)d_in[18];
    const float* b_vc    = (const float*)d_in[19];
    const float* W_out   = (const float*)d_in[20];
    const float* b_out   = (const float*)d_in[21];
    const int* surf_idx  = (const int*)d_in[22];
    const int* velo_idx  = (const int*)d_in[23];
    const int* first_lap = (const int*)d_in[24];
    const int* closest   = (const int*)d_in[25];
    const int* labels    = (const int*)d_in[26];
    float* out = (float*)d_out;
    float* ws  = (float*)d_ws;

    size_t o = 0;
    float* fx   = ws + o;  o += (size_t)N_TOT*512;
    float* xm   = ws + o;  o += (size_t)N_TOT*512;
    float* O1   = ws + o;  o += (size_t)HEADS*NQ1*64;   // = Op0, merged in place
    float* Op1  = ws + o;  o += (size_t)HEADS*NQ1*64;
    float2* Ml0 = (float2*)(ws + o); o += (size_t)HEADS*NQ1*2;
    float2* Ml1 = (float2*)(ws + o); o += (size_t)HEADS*NQ1*2;
    const size_t BFSZ = (size_t)HEADS*NQP*64/2;   // ushort count / 2 = float slots
    u16* Qhi = (u16*)(ws + o); o += BFSZ;
    u16* Qlo = (u16*)(ws + o); o += BFSZ;
    u16* Khi = (u16*)(ws + o); o += BFSZ;
    u16* Klo = (u16*)(ws + o); o += BFSZ;
    u16* Vthi= (u16*)(ws + o); o += BFSZ;
    u16* Vtlo= (u16*)(ws + o); o += BFSZ;
    const size_t WSPL = (size_t)512*512/2;        // u16 count / 2
    u16* Wfxh = (u16*)(ws + o); o += WSPL;
    u16* Wfxl = (u16*)(ws + o); o += WSPL;
    u16* Wxh  = (u16*)(ws + o); o += WSPL;
    u16* Wxl  = (u16*)(ws + o); o += WSPL;
    u16* Woh  = (u16*)(ws + o); o += WSPL;
    u16* Wol  = (u16*)(ws + o); o += WSPL;
    float* tokens = ws + o; o += 64*512;
    float* tln  = ws + o;  o += 64*512;
    float* q2   = ws + o;  o += 8*64*64;
    float* k2   = ws + o;  o += 8*64*64;
    float* v2   = ws + o;  o += 8*64*64;
    float* ot   = ws + o;  o += 8*64*64;
    float* osurf= ws + o;  o += 4*512;
    float* ovelo= ws + o;  o += 60*512;
    float* cs   = ws + o;  o += (size_t)NS*4;
    float* cv   = ws + o;  o += (size_t)NV*60;
    float* cc   = ws + o;  o += (size_t)NS*60;
    int* tok_of = (int*)(ws + o); o += SK + NV;
    int* src_of = (int*)(ws + o); o += SK + NV;
    float* part = ws + o;  o += (size_t)2*64*64*256;
    float* nf = fx;  // fx dead after k_qkv1 + k_tokens_accum; reuse as new_feature

    (void)in_sizes; (void)n_in; (void)out_size; (void)ws_size;

    k_split_wT<<<dim3(16,16,3), 256, 0, stream>>>(W_fx, W_x, W_out,
                                                  Wfxh, Wfxl, Wxh, Wxl, Woh, Wol);
    k_mm_bf16s<<<dim3(8, 252), 256, 0, stream>>>(x, Wfxh, Wfxl, b_fx, fx, N_TOT);
    k_mm_bf16s<<<dim3(8, 252), 256, 0, stream>>>(x, Wxh,  Wxl,  b_x,  xm, N_TOT);
    k_bucket_prep<<<126, 256, 0, stream>>>(labels, closest, surf_idx, velo_idx, onion, tok_of, src_of);
    k_qkv1<<<dim3(66, 8), 256, 0, stream>>>(fx, surf_idx, velo_idx, first_lap, Wq1, Wk1, Wv1,
                                            Qhi, Qlo, Khi, Klo, Vthi, Vtlo);
    k_attn1<<<dim3(33, 8, 2), 256, 0, stream>>>(Qhi, Qlo, Khi, Klo, Vthi, Vtlo,
                                                O1, Op1, Ml0, Ml1);
    k_attn_merge<<<(HEADS*NQ1*16 + 255)/256, 256, 0, stream>>>(O1, Op1, Ml0, Ml1, O1);
    k_tokens_accum<<<dim3(2, 64), 256, 0, stream>>>(fx, tok_of, src_of, part);
    k_tokens_reduce<<<128, 256, 0, stream>>>(part, tokens);
    k_ln<<<2, 256, 0, stream>>>(tokens, gamma, beta, tln);
    k_qkv2<<<8, 256, 0, stream>>>(tln, Wq, Wk, Wv, q2, k2, v2);
    k_attn2<<<8, 256, 0, stream>>>(q2, k2, v2, ot);
    k_build_ov<<<128, 256, 0, stream>>>(ot, osurf, ovelo);
    k_coef_surf<<<231, 256, 0, stream>>>(xm, surf_idx, W_ws, b_ws, W_vc, b_vc, cs, cc);
    k_coef_velo<<<1782, 256, 0, stream>>>(xm, velo_idx, W_vv, b_vv, cv);
    k_feat_velo<<<1782, 256, 0, stream>>>(cv, ovelo, O1, velo_idx, nf);
    k_feat_surf<<<231, 256, 0, stream>>>(cs, cc, osurf, ovelo, O1, surf_idx, nf);
    k_mm_bf16s<<<dim3(8, 252), 256, 0, stream>>>(nf, Woh, Wol, b_out, out, N_TOT);
}

// Round 5
// 1251.839 us; speedup vs baseline: 1.0519x; 1.0519x over previous
//
#include <hip/hip_runtime.h>

#define N_TOT 32186
#define NV    28504
#define NS    3682
#define DIM   512
#define HEADS 8
#define DH    64
#define FL    500
#define NQ1   4182   /* FL + NS */
#define NQP   4224   /* NQ1 padded to multiple of 64 */
#define KSPL  2112   /* split-K boundary for attn1 (33 chunks of 64) */
#define SK    3586
#define NTOK  64
#define ONION 15
#define SC    4
#define SCALE 0.125f
#define EPS   1e-5f

typedef unsigned short u16;
typedef __bf16 bf16x8 __attribute__((ext_vector_type(8)));
typedef float  f32x4  __attribute__((ext_vector_type(4)));

static __device__ inline void bsplit(float f, u16& hi, u16& lo) {
    __bf16 h = (__bf16)f;
    __bf16 l = (__bf16)(f - (float)h);
    hi = __builtin_bit_cast(u16, h);
    lo = __builtin_bit_cast(u16, l);
}
static __device__ inline u16 b16(float f) {
    return __builtin_bit_cast(u16, (__bf16)f);
}
static __device__ inline uint2 pk2(const u16* s) {
    uint2 w;
    w.x = (unsigned)s[0] | ((unsigned)s[1] << 16);
    w.y = (unsigned)s[2] | ((unsigned)s[3] << 16);
    return w;
}

// ---------------------------------------------------------------------------
// K0: split 3 weight matrices (512x512) into transposed bf16 hi/lo
// ---------------------------------------------------------------------------
__global__ __launch_bounds__(256) void k_split_wT(
    const float* __restrict__ W0, const float* __restrict__ W1, const float* __restrict__ W2,
    u16* __restrict__ h0, u16* __restrict__ l0,
    u16* __restrict__ h1, u16* __restrict__ l1,
    u16* __restrict__ h2, u16* __restrict__ l2)
{
    const float* W = (blockIdx.z == 0) ? W0 : (blockIdx.z == 1) ? W1 : W2;
    u16* th = (blockIdx.z == 0) ? h0 : (blockIdx.z == 1) ? h1 : h2;
    u16* tl = (blockIdx.z == 0) ? l0 : (blockIdx.z == 1) ? l1 : l2;
    __shared__ float T[32][33];
    const int tid = threadIdx.x;
    const int k0 = blockIdx.x*32, n0 = blockIdx.y*32;
    {
        int r = tid >> 3, c = (tid & 7) << 2;
        *(float4*)&T[r][c] = *(const float4*)(W + (size_t)(k0+r)*512 + n0 + c);
    }
    __syncthreads();
    int n = tid >> 3, kk = (tid & 7) << 2;
    u16 hh[4], ll[4];
    #pragma unroll
    for (int j = 0; j < 4; ++j) bsplit(T[kk+j][n], hh[j], ll[j]);
    *(uint2*)(th + (size_t)(n0+n)*512 + k0 + kk) = pk2(hh);
    *(uint2*)(tl + (size_t)(n0+n)*512 + k0 + kk) = pk2(ll);
}

// ---------------------------------------------------------------------------
// K1: C = A @ B + bias via split-bf16 MFMA (hh + hl + lh).
// ---------------------------------------------------------------------------
__global__ __launch_bounds__(256) void k_mm_bf16s(const float* __restrict__ A,
    const u16* __restrict__ Bth, const u16* __restrict__ Btl,
    const float* __restrict__ bias, float* __restrict__ C, int M)
{
    __shared__ __align__(16) u16 Ash[128][72], Asl[128][72];
    __shared__ __align__(16) u16 Bsh[64][72],  Bsl[64][72];
    const int tid = threadIdx.x;
    const int wave = tid >> 6, lane = tid & 63;
    const int m = lane & 15, quad = lane >> 4;
    const int bn = blockIdx.x * 64;
    const int bm = blockIdx.y * 128;
    const int wm = wave * 32;

    const int ar = tid >> 1;
    const int ac = (tid & 1) << 5;
    const int br = tid >> 2;
    const int bc = (tid & 3) << 4;

    f32x4 acc[2][4];
    #pragma unroll
    for (int mt = 0; mt < 2; ++mt)
        #pragma unroll
        for (int nt = 0; nt < 4; ++nt)
            #pragma unroll
            for (int r = 0; r < 4; ++r) acc[mt][nt][r] = 0.f;

    float4 pa[8];
    uint4 pbh[2], pbl[2];
    {
        bool va = (bm + ar) < M;
        const float* ap = A + (size_t)(bm+ar)*512 + ac;
        #pragma unroll
        for (int u = 0; u < 8; ++u)
            pa[u] = va ? *(const float4*)(ap + u*4) : float4{0,0,0,0};
        size_t bb = (size_t)(bn+br)*512 + bc;
        pbh[0] = *(const uint4*)(Bth + bb); pbh[1] = *(const uint4*)(Bth + bb + 8);
        pbl[0] = *(const uint4*)(Btl + bb); pbl[1] = *(const uint4*)(Btl + bb + 8);
    }

    for (int k0 = 0; k0 < 512; k0 += 64) {
        __syncthreads();
        #pragma unroll
        for (int u = 0; u < 8; ++u) {
            u16 hh[4], ll[4];
            bsplit(pa[u].x, hh[0], ll[0]);
            bsplit(pa[u].y, hh[1], ll[1]);
            bsplit(pa[u].z, hh[2], ll[2]);
            bsplit(pa[u].w, hh[3], ll[3]);
            *(uint2*)&Ash[ar][ac + u*4] = pk2(hh);
            *(uint2*)&Asl[ar][ac + u*4] = pk2(ll);
        }
        *(uint4*)&Bsh[br][bc]   = pbh[0];  *(uint4*)&Bsh[br][bc+8] = pbh[1];
        *(uint4*)&Bsl[br][bc]   = pbl[0];  *(uint4*)&Bsl[br][bc+8] = pbl[1];
        __syncthreads();
        const int kn = k0 + 64;
        if (kn < 512) {
            bool va = (bm + ar) < M;
            const float* ap = A + (size_t)(bm+ar)*512 + kn + ac;
            #pragma unroll
            for (int u = 0; u < 8; ++u)
                pa[u] = va ? *(const float4*)(ap + u*4) : float4{0,0,0,0};
            size_t bb = (size_t)(bn+br)*512 + kn + bc;
            pbh[0] = *(const uint4*)(Bth + bb); pbh[1] = *(const uint4*)(Bth + bb + 8);
            pbl[0] = *(const uint4*)(Btl + bb); pbl[1] = *(const uint4*)(Btl + bb + 8);
        }
        #pragma unroll
        for (int ks = 0; ks < 2; ++ks) {
            bf16x8 ah[2], al[2];
            #pragma unroll
            for (int mt = 0; mt < 2; ++mt) {
                ah[mt] = *(const bf16x8*)&Ash[wm + mt*16 + m][ks*32 + quad*8];
                al[mt] = *(const bf16x8*)&Asl[wm + mt*16 + m][ks*32 + quad*8];
            }
            bf16x8 bh[4], bl[4];
            #pragma unroll
            for (int nt = 0; nt < 4; ++nt) {
                bh[nt] = *(const bf16x8*)&Bsh[nt*16 + m][ks*32 + quad*8];
                bl[nt] = *(const bf16x8*)&Bsl[nt*16 + m][ks*32 + quad*8];
            }
            #pragma unroll
            for (int mt = 0; mt < 2; ++mt)
                #pragma unroll
                for (int nt = 0; nt < 4; ++nt)
                    acc[mt][nt] = __builtin_amdgcn_mfma_f32_16x16x32_bf16(ah[mt], bh[nt], acc[mt][nt], 0,0,0);
            #pragma unroll
            for (int mt = 0; mt < 2; ++mt)
                #pragma unroll
                for (int nt = 0; nt < 4; ++nt)
                    acc[mt][nt] = __builtin_amdgcn_mfma_f32_16x16x32_bf16(ah[mt], bl[nt], acc[mt][nt], 0,0,0);
            #pragma unroll
            for (int mt = 0; mt < 2; ++mt)
                #pragma unroll
                for (int nt = 0; nt < 4; ++nt)
                    acc[mt][nt] = __builtin_amdgcn_mfma_f32_16x16x32_bf16(al[mt], bh[nt], acc[mt][nt], 0,0,0);
        }
    }

    #pragma unroll
    for (int mt = 0; mt < 2; ++mt)
        #pragma unroll
        for (int nt = 0; nt < 4; ++nt) {
            float bsv = bias[bn + nt*16 + m];
            #pragma unroll
            for (int r = 0; r < 4; ++r) {
                int row = bm + wm + mt*16 + quad*4 + r;
                if (row < M)
                    C[(size_t)row*512 + bn + nt*16 + m] = acc[mt][nt][r] + bsv;
            }
        }
}

// ---------------------------------------------------------------------------
// K2: qkv for attention-1, plain bf16 outputs:
//   Qb[h][tok][e] (pre-scaled by 0.125), Kb[h][tok][e], Vt[h][e][tok] (transposed)
// ---------------------------------------------------------------------------
__global__ __launch_bounds__(256) void k_qkv1(const float* __restrict__ fx,
    const int* __restrict__ surf_idx, const int* __restrict__ velo_idx,
    const int* __restrict__ first_lap,
    const float* __restrict__ Wq, const float* __restrict__ Wk, const float* __restrict__ Wv,
    u16* __restrict__ Qb, u16* __restrict__ Kb, u16* __restrict__ Vt)
{
    __shared__ __align__(16) float As[16][64];
    __shared__ __align__(16) float Bs[3][16][64];
    const int tid = threadIdx.x;
    const int h = blockIdx.y;
    const int r0 = blockIdx.x * 64;
    const int tx = tid & 15, ty = tid >> 4;
    const int lr = tid >> 2, lc = (tid & 3) << 2;
    const int rr = r0 + lr;
    long src = -1;
    if (rr < NQ1) src = (rr < FL) ? velo_idx[first_lap[rr]] : surf_idx[rr - FL];
    float acc[3][4][4] = {};
    for (int k0 = 0; k0 < 64; k0 += 16) {
        float4 av = {0,0,0,0};
        if (src >= 0) av = *(const float4*)(fx + (size_t)src*512 + h*64 + k0 + lc);
        As[lc+0][lr]=av.x; As[lc+1][lr]=av.y; As[lc+2][lr]=av.z; As[lc+3][lr]=av.w;
        const int wr = tid >> 4, wc = (tid & 15) << 2;
        *(float4*)&Bs[0][wr][wc] = *(const float4*)(Wq + (k0+wr)*64 + wc);
        *(float4*)&Bs[1][wr][wc] = *(const float4*)(Wk + (k0+wr)*64 + wc);
        *(float4*)&Bs[2][wr][wc] = *(const float4*)(Wv + (k0+wr)*64 + wc);
        __syncthreads();
        #pragma unroll
        for (int kk = 0; kk < 16; ++kk) {
            float4 a = *(const float4*)&As[kk][ty<<2];
            const float aa[4] = {a.x,a.y,a.z,a.w};
            #pragma unroll
            for (int mm = 0; mm < 3; ++mm) {
                float4 bv = *(const float4*)&Bs[mm][kk][tx<<2];
                const float bb[4] = {bv.x,bv.y,bv.z,bv.w};
                #pragma unroll
                for (int i = 0; i < 4; ++i)
                    #pragma unroll
                    for (int j = 0; j < 4; ++j)
                        acc[mm][i][j] = fmaf(aa[i], bb[j], acc[mm][i][j]);
            }
        }
        __syncthreads();
    }
    #pragma unroll
    for (int i = 0; i < 4; ++i) {
        int r = r0 + (ty<<2) + i;   // always < NQP (grid covers 66*64=4224)
        size_t qb = ((size_t)h*NQP + r)*64 + (tx<<2);
        u16 q4[4], k4[4];
        #pragma unroll
        for (int j = 0; j < 4; ++j) {
            q4[j] = b16(acc[0][i][j]*SCALE);
            k4[j] = b16(acc[1][i][j]);
        }
        *(uint2*)(Qb + qb) = pk2(q4);
        *(uint2*)(Kb + qb) = pk2(k4);
        #pragma unroll
        for (int j = 0; j < 4; ++j)
            Vt[((size_t)h*64 + (tx<<2) + j)*NQP + r] = b16(acc[2][i][j]);
    }
}

// ---------------------------------------------------------------------------
// K3: plain-bf16 MFMA flash attention, split-K x2.
// grid (33, 8, 2), block 256 (4 waves), 32 q-rows/wave. LDS ~37 KB -> 4 blk/CU.
// P stored as bf16 in per-wave LDS (no f32 round trip).
// ---------------------------------------------------------------------------
__global__ __launch_bounds__(256) void k_attn1(
    const u16* __restrict__ Qb, const u16* __restrict__ Kb, const u16* __restrict__ Vt,
    float* __restrict__ Op0, float* __restrict__ Op1,
    float2* __restrict__ Ml0, float2* __restrict__ Ml1)
{
    __shared__ __align__(16) u16 Ksh[64][72];
    __shared__ __align__(16) u16 Vsh[64][72];
    __shared__ __align__(16) u16 Ps[4][32][72];

    const int tid = threadIdx.x;
    const int wave = tid >> 6;
    const int lane = tid & 63;
    const int m = lane & 15, quad = lane >> 4;
    const int h = blockIdx.y;
    const int q0 = blockIdx.x*128 + wave*32;
    const int zz = blockIdx.z;
    const int kbeg = zz ? KSPL : 0;
    const int kend = zz ? NQ1 : KSPL;
    float*  Op = zz ? Op1 : Op0;
    float2* Ml = zz ? Ml1 : Ml0;

    const u16* Kg = Kb + (size_t)h*NQP*64;
    const u16* Vg = Vt + (size_t)h*64*NQP;

    bf16x8 qf[2][2];
    #pragma unroll
    for (int t = 0; t < 2; ++t)
        #pragma unroll
        for (int ks = 0; ks < 2; ++ks)
            qf[t][ks] = *(const bf16x8*)(Qb + ((size_t)h*NQP + q0 + t*16 + m)*64 + ks*32 + quad*8);

    const int sr = tid >> 2;           // 0..63
    const int sc = (tid & 3) << 4;     // 0,16,32,48 (u16 units)
    uint4 pre[4];
    {
        size_t kb = ((size_t)kbeg + sr)*64 + sc;
        pre[0] = *(const uint4*)(Kg + kb);  pre[1] = *(const uint4*)(Kg + kb + 8);
        size_t vb = (size_t)sr*NQP + kbeg + sc;
        pre[2] = *(const uint4*)(Vg + vb);  pre[3] = *(const uint4*)(Vg + vb + 8);
    }

    f32x4 Oc[2][4];
    float mrun[2][4], lrun[2][4];
    #pragma unroll
    for (int t = 0; t < 2; ++t)
        #pragma unroll
        for (int r = 0; r < 4; ++r) {
            mrun[t][r] = -1e30f; lrun[t][r] = 0.f;
            #pragma unroll
            for (int dt = 0; dt < 4; ++dt) Oc[t][dt][r] = 0.f;
        }

    for (int k0 = kbeg; k0 < kend; k0 += 64) {
        __syncthreads();
        *(uint4*)&Ksh[sr][sc]   = pre[0];  *(uint4*)&Ksh[sr][sc+8] = pre[1];
        *(uint4*)&Vsh[sr][sc]   = pre[2];  *(uint4*)&Vsh[sr][sc+8] = pre[3];
        __syncthreads();
        const int kn = k0 + 64;
        if (kn < kend) {
            size_t kb = ((size_t)kn + sr)*64 + sc;
            pre[0] = *(const uint4*)(Kg + kb);  pre[1] = *(const uint4*)(Kg + kb + 8);
            size_t vb = (size_t)sr*NQP + kn + sc;
            pre[2] = *(const uint4*)(Vg + vb);  pre[3] = *(const uint4*)(Vg + vb + 8);
        }

        // ---- scores: 16 MFMAs
        f32x4 S[2][4];
        #pragma unroll
        for (int t = 0; t < 2; ++t)
            #pragma unroll
            for (int n = 0; n < 4; ++n)
                #pragma unroll
                for (int r = 0; r < 4; ++r) S[t][n][r] = 0.f;
        #pragma unroll
        for (int ks = 0; ks < 2; ++ks) {
            bf16x8 kf[4];
            #pragma unroll
            for (int n = 0; n < 4; ++n)
                kf[n] = *(const bf16x8*)&Ksh[n*16 + m][ks*32 + quad*8];
            #pragma unroll
            for (int t = 0; t < 2; ++t)
                #pragma unroll
                for (int n = 0; n < 4; ++n)
                    S[t][n] = __builtin_amdgcn_mfma_f32_16x16x32_bf16(qf[t][ks], kf[n], S[t][n], 0,0,0);
        }
        if (kn > NQ1) {   // mask padded keys (last chunk of segment 1)
            #pragma unroll
            for (int n = 0; n < 4; ++n)
                if (k0 + n*16 + m >= NQ1) {
                    #pragma unroll
                    for (int t = 0; t < 2; ++t)
                        #pragma unroll
                        for (int r = 0; r < 4; ++r) S[t][n][r] = -1e30f;
                }
        }

        // ---- online softmax (rows quad*4+r, in registers)
        float alpha[2][4];
        #pragma unroll
        for (int t = 0; t < 2; ++t) {
            float sm[4];
            #pragma unroll
            for (int r = 0; r < 4; ++r) {
                float v = fmaxf(fmaxf(S[t][0][r], S[t][1][r]), fmaxf(S[t][2][r], S[t][3][r]));
                v = fmaxf(v, __shfl_xor(v, 1));
                v = fmaxf(v, __shfl_xor(v, 2));
                v = fmaxf(v, __shfl_xor(v, 4));
                v = fmaxf(v, __shfl_xor(v, 8));
                float mn = fmaxf(mrun[t][r], v);
                alpha[t][r] = __expf(mrun[t][r] - mn);
                mrun[t][r] = mn;
                sm[r] = 0.f;
            }
            #pragma unroll
            for (int n = 0; n < 4; ++n)
                #pragma unroll
                for (int r = 0; r < 4; ++r) {
                    float p = __expf(S[t][n][r] - mrun[t][r]);
                    S[t][n][r] = p;
                    sm[r] += p;
                }
            #pragma unroll
            for (int r = 0; r < 4; ++r) {
                float v = sm[r];
                v += __shfl_xor(v, 1);
                v += __shfl_xor(v, 2);
                v += __shfl_xor(v, 4);
                v += __shfl_xor(v, 8);
                lrun[t][r] = lrun[t][r]*alpha[t][r] + v;
            }
        }
        #pragma unroll
        for (int t = 0; t < 2; ++t)
            #pragma unroll
            for (int dt = 0; dt < 4; ++dt)
                #pragma unroll
                for (int r = 0; r < 4; ++r) Oc[t][dt][r] *= alpha[t][r];

        // ---- P -> per-wave LDS as bf16 (C-layout scatter; wave-private)
        #pragma unroll
        for (int t = 0; t < 2; ++t)
            #pragma unroll
            for (int n = 0; n < 4; ++n)
                #pragma unroll
                for (int r = 0; r < 4; ++r)
                    Ps[wave][t*16 + quad*4 + r][n*16 + m] = b16(S[t][n][r]);

        // ---- AV: 16 MFMAs (P read back as A-frags, V^T as B-frags)
        #pragma unroll
        for (int ks = 0; ks < 2; ++ks) {
            bf16x8 af[2];
            #pragma unroll
            for (int t = 0; t < 2; ++t)
                af[t] = *(const bf16x8*)&Ps[wave][t*16 + m][ks*32 + quad*8];
            bf16x8 vf[4];
            #pragma unroll
            for (int dt = 0; dt < 4; ++dt)
                vf[dt] = *(const bf16x8*)&Vsh[dt*16 + m][ks*32 + quad*8];
            #pragma unroll
            for (int t = 0; t < 2; ++t)
                #pragma unroll
                for (int dt = 0; dt < 4; ++dt)
                    Oc[t][dt] = __builtin_amdgcn_mfma_f32_16x16x32_bf16(af[t], vf[dt], Oc[t][dt], 0,0,0);
        }
    }

    // epilogue: unnormalized partial + (m,l) per row
    #pragma unroll
    for (int t = 0; t < 2; ++t) {
        #pragma unroll
        for (int r = 0; r < 4; ++r) {
            int q = q0 + t*16 + quad*4 + r;
            if (q < NQ1 && m == 0)
                Ml[(size_t)h*NQ1 + q] = make_float2(mrun[t][r], lrun[t][r]);
        }
        #pragma unroll
        for (int dt = 0; dt < 4; ++dt)
            #pragma unroll
            for (int r = 0; r < 4; ++r) {
                int q = q0 + t*16 + quad*4 + r;
                if (q < NQ1)
                    Op[((size_t)h*NQ1 + q)*64 + dt*16 + m] = Oc[t][dt][r];
            }
    }
}

// ---------------------------------------------------------------------------
// K3b: merge the two K-segments (exact online-softmax combine), in place.
// ---------------------------------------------------------------------------
__global__ __launch_bounds__(256) void k_attn_merge(
    const float* __restrict__ Op0, const float* __restrict__ Op1,
    const float2* __restrict__ Ml0, const float2* __restrict__ Ml1,
    float* __restrict__ O)
{
    int idx = blockIdx.x*256 + threadIdx.x;
    if (idx >= HEADS*NQ1*16) return;
    int row = idx >> 4, d4 = (idx & 15) << 2;
    float2 a = Ml0[row], b = Ml1[row];
    float mx = fmaxf(a.x, b.x);
    float e0 = __expf(a.x - mx), e1 = __expf(b.x - mx);
    float inv = 1.f / (a.y*e0 + b.y*e1);
    float4 o0 = *(const float4*)(Op0 + (size_t)row*64 + d4);
    float4 o1 = *(const float4*)(Op1 + (size_t)row*64 + d4);
    float4 r;
    r.x = (o0.x*e0 + o1.x*e1)*inv;
    r.y = (o0.y*e0 + o1.y*e1)*inv;
    r.z = (o0.z*e0 + o1.z*e1)*inv;
    r.w = (o0.w*e0 + o1.w*e1)*inv;
    *(float4*)(O + (size_t)row*64 + d4) = r;
}

// ---------------------------------------------------------------------------
// K4a: per source row -> (token id, fx row)
// ---------------------------------------------------------------------------
__global__ void k_bucket_prep(const int* __restrict__ labels, const int* __restrict__ closest,
    const int* __restrict__ surf_idx, const int* __restrict__ velo_idx,
    const float* __restrict__ onion, int* __restrict__ tok_of, int* __restrict__ src_of)
{
    int r = blockIdx.x*256 + threadIdx.x;
    if (r < SK) {
        tok_of[r] = labels[r];
        int s = (r < 16) ? r : r + 96;
        src_of[r] = surf_idx[s];
    } else if (r < SK + NV) {
        int p = r - SK;
        int cl = labels[closest[p]];
        int l = 0;
        #pragma unroll
        for (int q = 1; q < ONION; ++q)
            if (onion[(size_t)q*NV + p] != 0.f) l = q;
        tok_of[r] = SC + l*SC + cl;
        src_of[r] = velo_idx[p];
    }
}

// ---------------------------------------------------------------------------
// K4b: token pooling partials
// ---------------------------------------------------------------------------
__global__ __launch_bounds__(256) void k_tokens_accum(const float* __restrict__ fx,
    const int* __restrict__ tok_of, const int* __restrict__ src_of, float* __restrict__ part)
{
    __shared__ float acc[64][256];
    const int tid = threadIdx.x;
    for (int i = tid; i < 64*256; i += 256) ((float*)acc)[i] = 0.f;
    __syncthreads();
    const int d0 = blockIdx.x << 8;
    const int R = SK + NV;
    const int per = (R + gridDim.y - 1) / gridDim.y;
    int rs = blockIdx.y * per;
    int re = rs + per; if (re > R) re = R;
    const float wS = 1.f / SK, wV = 1.f / NV;
    int r = rs;
    for (; r + 4 <= re; r += 4) {
        int t0 = tok_of[r], t1 = tok_of[r+1], t2 = tok_of[r+2], t3 = tok_of[r+3];
        int s0 = src_of[r], s1 = src_of[r+1], s2 = src_of[r+2], s3 = src_of[r+3];
        float v0 = fx[(size_t)s0*512 + d0 + tid] * ((r   < SK) ? wS : wV);
        float v1 = fx[(size_t)s1*512 + d0 + tid] * ((r+1 < SK) ? wS : wV);
        float v2 = fx[(size_t)s2*512 + d0 + tid] * ((r+2 < SK) ? wS : wV);
        float v3 = fx[(size_t)s3*512 + d0 + tid] * ((r+3 < SK) ? wS : wV);
        acc[t0][tid] += v0; acc[t1][tid] += v1; acc[t2][tid] += v2; acc[t3][tid] += v3;
    }
    for (; r < re; ++r) {
        float v = fx[(size_t)src_of[r]*512 + d0 + tid] * ((r < SK) ? wS : wV);
        acc[tok_of[r]][tid] += v;
    }
    __syncthreads();
    float* dst = part + ((size_t)blockIdx.x*gridDim.y + blockIdx.y)*64*256;
    for (int i = tid; i < 64*256; i += 256) dst[i] = acc[i >> 8][i & 255];
}

__global__ void k_tokens_reduce(const float* __restrict__ part, float* __restrict__ tokens)
{
    int idx = blockIdx.x*256 + threadIdx.x;   // < 64*512
    int t = idx >> 9;
    int dg = idx & 511;
    int cc = dg >> 8, d = dg & 255;
    float s = 0.f;
    for (int ch = 0; ch < 64; ++ch)
        s += part[(((size_t)cc*64 + ch)*64 + t)*256 + d];
    tokens[idx] = s;
}

// ---------------------------------------------------------------------------
// K5a: LayerNorm across the 64 tokens, per channel
// ---------------------------------------------------------------------------
__global__ void k_ln(const float* __restrict__ tokens, const float* __restrict__ gamma,
    const float* __restrict__ beta, float* __restrict__ tln)
{
    int ch = blockIdx.x*256 + threadIdx.x;
    if (ch >= 512) return;
    float vals[64];
    float mu = 0.f;
    #pragma unroll
    for (int t = 0; t < 64; ++t) { vals[t] = tokens[t*512 + ch]; mu += vals[t]; }
    mu *= (1.f/64.f);
    float var = 0.f;
    #pragma unroll
    for (int t = 0; t < 64; ++t) { float d = vals[t]-mu; var = fmaf(d, d, var); }
    var *= (1.f/64.f);
    float rstd = rsqrtf(var + EPS);
    #pragma unroll
    for (int t = 0; t < 64; ++t)
        tln[t*512 + ch] = (vals[t]-mu)*rstd*gamma[t] + beta[t];
}

// ---------------------------------------------------------------------------
// K5b: q2/k2/v2[h][t][e] for the 64-token attention
// ---------------------------------------------------------------------------
__global__ __launch_bounds__(256) void k_qkv2(const float* __restrict__ tln,
    const float* __restrict__ Wq, const float* __restrict__ Wk, const float* __restrict__ Wv,
    float* __restrict__ q2, float* __restrict__ k2, float* __restrict__ v2)
{
    __shared__ float Ts[64][64];
    __shared__ float Wt[3][64][65];
    const int h = blockIdx.x, tid = threadIdx.x;
    for (int i = tid; i < 4096; i += 256) {
        int t = i >> 6, d = i & 63;
        Ts[t][d] = tln[t*512 + h*64 + d];
    }
    for (int i = tid; i < 4096; i += 256) {
        int d = i >> 6, e = i & 63;
        Wt[0][e][d] = Wq[i]; Wt[1][e][d] = Wk[i]; Wt[2][e][d] = Wv[i];
    }
    __syncthreads();
    for (int o = tid; o < 4096; o += 256) {
        int t = o >> 6, e = o & 63;
        float s0 = 0.f, s1 = 0.f, s2 = 0.f;
        for (int d = 0; d < 64; ++d) {
            float xv = Ts[t][d];
            s0 = fmaf(xv, Wt[0][e][d], s0);
            s1 = fmaf(xv, Wt[1][e][d], s1);
            s2 = fmaf(xv, Wt[2][e][d], s2);
        }
        size_t idx = (size_t)h*4096 + o;
        q2[idx] = s0; k2[idx] = s1; v2[idx] = s2;
    }
}

// ---------------------------------------------------------------------------
// K5c: 64-token attention per head
// ---------------------------------------------------------------------------
__global__ __launch_bounds__(256) void k_attn2(const float* __restrict__ q2,
    const float* __restrict__ k2, const float* __restrict__ v2, float* __restrict__ ot)
{
    __shared__ float Qs[64][65], Ks[64][65], Vs[64][65], Ps2[64][65];
    const int h = blockIdx.x, tid = threadIdx.x;
    const float* qh = q2 + (size_t)h*4096;
    const float* kh = k2 + (size_t)h*4096;
    const float* vh = v2 + (size_t)h*4096;
    for (int i = tid; i < 4096; i += 256) {
        int t = i >> 6, e = i & 63;
        Qs[t][e] = qh[i]; Ks[t][e] = kh[i]; Vs[t][e] = vh[i];
    }
    __syncthreads();
    for (int o = tid; o < 4096; o += 256) {
        int t = o >> 6, j = o & 63;
        float s = 0.f;
        for (int e = 0; e < 64; ++e) s = fmaf(Qs[t][e], Ks[j][e], s);
        Ps2[t][j] = s * SCALE;
    }
    __syncthreads();
    if (tid < 64) {
        float mx = -1e30f;
        for (int j = 0; j < 64; ++j) mx = fmaxf(mx, Ps2[tid][j]);
        float sum = 0.f;
        for (int j = 0; j < 64; ++j) { float p = __expf(Ps2[tid][j]-mx); Ps2[tid][j] = p; sum += p; }
        float inv = 1.f / sum;
        for (int j = 0; j < 64; ++j) Ps2[tid][j] *= inv;
    }
    __syncthreads();
    for (int o = tid; o < 4096; o += 256) {
        int t = o >> 6, e = o & 63;
        float s = 0.f;
        for (int j = 0; j < 64; ++j) s = fmaf(Ps2[t][j], Vs[j][e], s);
        ot[(size_t)h*4096 + o] = s;
    }
}

// ---------------------------------------------------------------------------
// K5d: out_surf (flat reshape) and out_velo (head-concat) from out_tok
// ---------------------------------------------------------------------------
__global__ void k_build_ov(const float* __restrict__ ot, float* __restrict__ osurf,
    float* __restrict__ ovelo)
{
    int i = blockIdx.x*256 + threadIdx.x;
    if (i < 2048) {
        osurf[i] = ot[((i >> 8) << 12) + (i & 255)];
    }
    int g = i - 2048;
    if (g >= 0 && g < 60*512) {
        int j = g >> 9, cch = g & 511;
        int hh = cch >> 6, d = cch & 63;
        ovelo[g] = ot[(size_t)hh*4096 + (SC + j)*64 + d];
    }
}

// ---------------------------------------------------------------------------
// K6a: cs = surf_x@W_ws+b_ws  and  cc = surf_x@W_vc+b_vc (64-col concat)
// ---------------------------------------------------------------------------
__global__ __launch_bounds__(256) void k_coef_surf(const float* __restrict__ xm,
    const int* __restrict__ surf_idx,
    const float* __restrict__ W_ws, const float* __restrict__ b_ws,
    const float* __restrict__ W_vc, const float* __restrict__ b_vc,
    float* __restrict__ cs, float* __restrict__ cc)
{
    __shared__ __align__(16) float As[16][516];
    __shared__ float Ws[128][64];
    const int tid = threadIdx.x;
    const int s0 = blockIdx.x * 16;
    for (int i = tid; i < 16*128; i += 256) {
        int r = i >> 7, c4 = (i & 127) << 2;
        float4 a = {0,0,0,0};
        int s = s0 + r;
        if (s < NS) a = *(const float4*)(xm + (size_t)surf_idx[s]*512 + c4);
        *(float4*)&As[r][c4] = a;
    }
    const int c = tid & 63, rg = tid >> 6;
    float acc[4] = {0,0,0,0};
    for (int k0 = 0; k0 < 512; k0 += 128) {
        __syncthreads();
        for (int i = tid; i < 128*64; i += 256) {
            int kk = i >> 6, cw = i & 63;
            int k = k0 + kk;
            Ws[kk][cw] = (cw < 4) ? W_ws[k*4 + cw] : W_vc[k*60 + (cw-4)];
        }
        __syncthreads();
        #pragma unroll 8
        for (int kk = 0; kk < 128; kk += 4) {
            float w0 = Ws[kk][c], w1 = Ws[kk+1][c], w2 = Ws[kk+2][c], w3 = Ws[kk+3][c];
            #pragma unroll
            for (int u = 0; u < 4; ++u) {
                float4 a = *(const float4*)&As[rg + (u<<2)][k0 + kk];
                acc[u] = fmaf(a.x,w0, fmaf(a.y,w1, fmaf(a.z,w2, fmaf(a.w,w3, acc[u]))));
            }
        }
    }
    #pragma unroll
    for (int u = 0; u < 4; ++u) {
        int s = s0 + rg + (u<<2);
        if (s >= NS) continue;
        if (c < 4) cs[(size_t)s*4 + c] = acc[u] + b_ws[c];
        else cc[(size_t)s*60 + (c-4)] = acc[u] + b_vc[c-4];
    }
}

// ---------------------------------------------------------------------------
// K6b: cv = velo_x@W_vv+b_vv
// ---------------------------------------------------------------------------
__global__ __launch_bounds__(256) void k_coef_velo(const float* __restrict__ xm,
    const int* __restrict__ velo_idx, const float* __restrict__ W,
    const float* __restrict__ b, float* __restrict__ cv)
{
    __shared__ __align__(16) float As[16][516];
    __shared__ float Ws[128][64];
    const int tid = threadIdx.x;
    const int v0 = blockIdx.x * 16;
    for (int i = tid; i < 16*128; i += 256) {
        int r = i >> 7, c4 = (i & 127) << 2;
        float4 a = {0,0,0,0};
        int v = v0 + r;
        if (v < NV) a = *(const float4*)(xm + (size_t)velo_idx[v]*512 + c4);
        *(float4*)&As[r][c4] = a;
    }
    const int c = tid & 63, rg = tid >> 6;
    float acc[4] = {0,0,0,0};
    for (int k0 = 0; k0 < 512; k0 += 128) {
        __syncthreads();
        for (int i = tid; i < 128*64; i += 256) {
            int kk = i >> 6, cw = i & 63;
            Ws[kk][cw] = (cw < 60) ? W[(size_t)(k0+kk)*60 + cw] : 0.f;
        }
        __syncthreads();
        #pragma unroll 8
        for (int kk = 0; kk < 128; kk += 4) {
            float w0 = Ws[kk][c], w1 = Ws[kk+1][c], w2 = Ws[kk+2][c], w3 = Ws[kk+3][c];
            #pragma unroll
            for (int u = 0; u < 4; ++u) {
                float4 a = *(const float4*)&As[rg + (u<<2)][k0 + kk];
                acc[u] = fmaf(a.x,w0, fmaf(a.y,w1, fmaf(a.z,w2, fmaf(a.w,w3, acc[u]))));
            }
        }
    }
    if (c < 60) {
        float bb = b[c];
        #pragma unroll
        for (int u = 0; u < 4; ++u) {
            int v = v0 + rg + (u<<2);
            if (v < NV) cv[(size_t)v*60 + c] = acc[u] + bb;
        }
    }
}

// ---------------------------------------------------------------------------
// K7a: feat_velo = cv@out_velo (+ velo_first_lap rows<FL) -> nf scatter
// ---------------------------------------------------------------------------
__global__ __launch_bounds__(256) void k_feat_velo(const float* __restrict__ cv,
    const float* __restrict__ ovelo, const float* __restrict__ O1,
    const int* __restrict__ velo_idx, float* __restrict__ nf)
{
    __shared__ float Cs[16][64];
    const int tid = threadIdx.x;
    const int v0 = blockIdx.x * 16;
    for (int i = tid; i < 16*64; i += 256) {
        int r = i >> 6, j = i & 63;
        int v = v0 + r;
        Cs[r][j] = (j < 60 && v < NV) ? cv[(size_t)v*60 + j] : 0.f;
    }
    __syncthreads();
    const int c = tid, c2 = tid + 256;
    float a0[16], a1[16];
    #pragma unroll
    for (int r = 0; r < 16; ++r) { a0[r] = 0.f; a1[r] = 0.f; }
    #pragma unroll 4
    for (int j = 0; j < 60; ++j) {
        float e0 = ovelo[j*512 + c];
        float e1 = ovelo[j*512 + c2];
        #pragma unroll
        for (int r = 0; r < 16; ++r) {
            float cf = Cs[r][j];
            a0[r] = fmaf(cf, e0, a0[r]);
            a1[r] = fmaf(cf, e1, a1[r]);
        }
    }
    const int h0 = c >> 6, d0 = c & 63, h1 = c2 >> 6, d1 = c2 & 63;
    for (int r = 0; r < 16; ++r) {
        int v = v0 + r;
        if (v >= NV) break;
        float f0 = a0[r], f1 = a1[r];
        if (v < FL) {
            f0 += O1[((size_t)h0*NQ1 + v)*64 + d0];
            f1 += O1[((size_t)h1*NQ1 + v)*64 + d1];
        }
        size_t row = (size_t)velo_idx[v]*512;
        nf[row + c] = f0;
        nf[row + c2] = f1;
    }
}

// ---------------------------------------------------------------------------
// K7b: feat_surf = 0.5*(cs@out_surf + cc@out_velo) + surf_first_lap -> nf
// ---------------------------------------------------------------------------
__global__ __launch_bounds__(256) void k_feat_surf(const float* __restrict__ cs,
    const float* __restrict__ cc, const float* __restrict__ osurf,
    const float* __restrict__ ovelo, const float* __restrict__ O1,
    const int* __restrict__ surf_idx, float* __restrict__ nf)
{
    __shared__ float Cs[16][64];
    const int tid = threadIdx.x;
    const int s0 = blockIdx.x * 16;
    for (int i = tid; i < 16*64; i += 256) {
        int r = i >> 6, j = i & 63;
        int s = s0 + r;
        float v = 0.f;
        if (s < NS) v = (j < 4) ? cs[(size_t)s*4 + j] : cc[(size_t)s*60 + (j-4)];
        Cs[r][j] = v;
    }
    __syncthreads();
    const int c = tid, c2 = tid + 256;
    float a0[16], a1[16];
    #pragma unroll
    for (int r = 0; r < 16; ++r) { a0[r] = 0.f; a1[r] = 0.f; }
    #pragma unroll 4
    for (int j = 0; j < 64; ++j) {
        float e0 = (j < 4) ? osurf[j*512 + c]  : ovelo[(j-4)*512 + c];
        float e1 = (j < 4) ? osurf[j*512 + c2] : ovelo[(j-4)*512 + c2];
        #pragma unroll
        for (int r = 0; r < 16; ++r) {
            float cf = Cs[r][j];
            a0[r] = fmaf(cf, e0, a0[r]);
            a1[r] = fmaf(cf, e1, a1[r]);
        }
    }
    const int h0 = c >> 6, d0 = c & 63, h1 = c2 >> 6, d1 = c2 & 63;
    for (int r = 0; r < 16; ++r) {
        int s = s0 + r;
        if (s >= NS) break;
        float f0 = 0.5f*a0[r] + O1[((size_t)h0*NQ1 + FL + s)*64 + d0];
        float f1 = 0.5f*a1[r] + O1[((size_t)h1*NQ1 + FL + s)*64 + d1];
        size_t row = (size_t)surf_idx[s]*512;
        nf[row + c] = f0;
        nf[row + c2] = f1;
    }
}

// ---------------------------------------------------------------------------
extern "C" void kernel_launch(void* const* d_in, const int* in_sizes, int n_in,
                              void* d_out, int out_size, void* d_ws, size_t ws_size,
                              hipStream_t stream)
{
    const float* x       = (const float*)d_in[0];
    const float* onion   = (const float*)d_in[1];
    const float* W_fx    = (const float*)d_in[2];
    const float* b_fx    = (const float*)d_in[3];
    const float* W_x     = (const float*)d_in[4];
    const float* b_x     = (const float*)d_in[5];
    const float* Wq1     = (const float*)d_in[6];
    const float* Wk1     = (const float*)d_in[7];
    const float* Wv1     = (const float*)d_in[8];
    const float* Wq      = (const float*)d_in[9];
    const float* Wk      = (const float*)d_in[10];
    const float* Wv      = (const float*)d_in[11];
    const float* gamma   = (const float*)d_in[12];
    const float* beta    = (const float*)d_in[13];
    const float* W_ws    = (const float*)d_in[14];
    const float* b_ws    = (const float*)d_in[15];
    const float* W_vv    = (const float*)d_in[16];
    const float* b_vv    = (const float*)d_in[17];
    const float* W_vc    = (const float*)d_in[18];
    const float* b_vc    = (const float*)d_in[19];
    const float* W_out   = (const float*)d_in[20];
    const float* b_out   = (const float*)d_in[21];
    const int* surf_idx  = (const int*)d_in[22];
    const int* velo_idx  = (const int*)d_in[23];
    const int* first_lap = (const int*)d_in[24];
    const int* closest   = (const int*)d_in[25];
    const int* labels    = (const int*)d_in[26];
    float* out = (float*)d_out;
    float* ws  = (float*)d_ws;

    size_t o = 0;
    float* fx   = ws + o;  o += (size_t)N_TOT*512;
    float* xm   = ws + o;  o += (size_t)N_TOT*512;
    float* O1   = ws + o;  o += (size_t)HEADS*NQ1*64;   // = Op0, merged in place
    float* Op1  = ws + o;  o += (size_t)HEADS*NQ1*64;
    float2* Ml0 = (float2*)(ws + o); o += (size_t)HEADS*NQ1*2;
    float2* Ml1 = (float2*)(ws + o); o += (size_t)HEADS*NQ1*2;
    const size_t BFSZ = (size_t)HEADS*NQP*64/2;   // u16 count / 2 = float slots
    u16* Qb  = (u16*)(ws + o); o += BFSZ;
    u16* Kb  = (u16*)(ws + o); o += BFSZ;
    u16* Vt  = (u16*)(ws + o); o += BFSZ;
    const size_t WSPL = (size_t)512*512/2;        // u16 count / 2
    u16* Wfxh = (u16*)(ws + o); o += WSPL;
    u16* Wfxl = (u16*)(ws + o); o += WSPL;
    u16* Wxh  = (u16*)(ws + o); o += WSPL;
    u16* Wxl  = (u16*)(ws + o); o += WSPL;
    u16* Woh  = (u16*)(ws + o); o += WSPL;
    u16* Wol  = (u16*)(ws + o); o += WSPL;
    float* tokens = ws + o; o += 64*512;
    float* tln  = ws + o;  o += 64*512;
    float* q2   = ws + o;  o += 8*64*64;
    float* k2   = ws + o;  o += 8*64*64;
    float* v2   = ws + o;  o += 8*64*64;
    float* ot   = ws + o;  o += 8*64*64;
    float* osurf= ws + o;  o += 4*512;
    float* ovelo= ws + o;  o += 60*512;
    float* cs   = ws + o;  o += (size_t)NS*4;
    float* cv   = ws + o;  o += (size_t)NV*60;
    float* cc   = ws + o;  o += (size_t)NS*60;
    int* tok_of = (int*)(ws + o); o += SK + NV;
    int* src_of = (int*)(ws + o); o += SK + NV;
    float* part = ws + o;  o += (size_t)2*64*64*256;
    float* nf = fx;  // fx dead after k_qkv1 + k_tokens_accum; reuse as new_feature

    (void)in_sizes; (void)n_in; (void)out_size; (void)ws_size;

    k_split_wT<<<dim3(16,16,3), 256, 0, stream>>>(W_fx, W_x, W_out,
                                                  Wfxh, Wfxl, Wxh, Wxl, Woh, Wol);
    k_mm_bf16s<<<dim3(8, 252), 256, 0, stream>>>(x, Wfxh, Wfxl, b_fx, fx, N_TOT);
    k_mm_bf16s<<<dim3(8, 252), 256, 0, stream>>>(x, Wxh,  Wxl,  b_x,  xm, N_TOT);
    k_bucket_prep<<<126, 256, 0, stream>>>(labels, closest, surf_idx, velo_idx, onion, tok_of, src_of);
    k_qkv1<<<dim3(66, 8), 256, 0, stream>>>(fx, surf_idx, velo_idx, first_lap, Wq1, Wk1, Wv1,
                                            Qb, Kb, Vt);
    k_attn1<<<dim3(33, 8, 2), 256, 0, stream>>>(Qb, Kb, Vt, O1, Op1, Ml0, Ml1);
    k_attn_merge<<<(HEADS*NQ1*16 + 255)/256, 256, 0, stream>>>(O1, Op1, Ml0, Ml1, O1);
    k_tokens_accum<<<dim3(2, 64), 256, 0, stream>>>(fx, tok_of, src_of, part);
    k_tokens_reduce<<<128, 256, 0, stream>>>(part, tokens);
    k_ln<<<2, 256, 0, stream>>>(tokens, gamma, beta, tln);
    k_qkv2<<<8, 256, 0, stream>>>(tln, Wq, Wk, Wv, q2, k2, v2);
    k_attn2<<<8, 256, 0, stream>>>(q2, k2, v2, ot);
    k_build_ov<<<128, 256, 0, stream>>>(ot, osurf, ovelo);
    k_coef_surf<<<231, 256, 0, stream>>>(xm, surf_idx, W_ws, b_ws, W_vc, b_vc, cs, cc);
    k_coef_velo<<<1782, 256, 0, stream>>>(xm, velo_idx, W_vv, b_vv, cv);
    k_feat_velo<<<1782, 256, 0, stream>>>(cv, ovelo, O1, velo_idx, nf);
    k_feat_surf<<<231, 256, 0, stream>>>(cs, cc, osurf, ovelo, O1, surf_idx, nf);
    k_mm_bf16s<<<dim3(8, 252), 256, 0, stream>>>(nf, Woh, Wol, b_out, out, N_TOT);
}